// Round 3
// baseline (413.585 us; speedup 1.0000x reference)
//
#include <hip/hip_runtime.h>

typedef __bf16 bf16;
typedef __bf16 bf16x8 __attribute__((ext_vector_type(8)));
typedef float  f32x4  __attribute__((ext_vector_type(4)));

#define S 512
#define DD 768
#define LL 64
#define BB 4

__device__ __forceinline__ void async_copy16(const void* g, void* l) {
    __builtin_amdgcn_global_load_lds(
        (const __attribute__((address_space(1))) unsigned int*)g,
        (__attribute__((address_space(3))) unsigned int*)l,
        16, 0, 0);
}

__device__ __forceinline__ bf16x8 scale_cvt(float4 a, float4 b, float4 ua, float4 ub) {
    bf16x8 p;
    p[0] = (bf16)(a.x * ua.x); p[1] = (bf16)(a.y * ua.y);
    p[2] = (bf16)(a.z * ua.z); p[3] = (bf16)(a.w * ua.w);
    p[4] = (bf16)(b.x * ub.x); p[5] = (bf16)(b.y * ub.y);
    p[6] = (bf16)(b.z * ub.z); p[7] = (bf16)(b.w * ub.w);
    return p;
}

// ---------------- prepass 1: dep fp32 -> bf16 ----------------
__global__ void cvt_dep_kernel(const float* __restrict__ dep, bf16* __restrict__ out) {
    int idx = (blockIdx.x * 256 + threadIdx.x) * 8;
    float4 a = *(const float4*)(dep + idx);
    float4 c = *(const float4*)(dep + idx + 4);
    bf16x8 p;
    p[0] = (bf16)a.x; p[1] = (bf16)a.y; p[2] = (bf16)a.z; p[3] = (bf16)a.w;
    p[4] = (bf16)c.x; p[5] = (bf16)c.y; p[6] = (bf16)c.z; p[7] = (bf16)c.w;
    *(bf16x8*)(out + idx) = p;
}

// ---------------- prepass 2: t2h[b,l,i], t2d'[b,l,o] (+bias) ----------------
__global__ void t2_kernel(const float* __restrict__ head, const float* __restrict__ dep,
                          const float* __restrict__ W, const float* __restrict__ bias,
                          float* __restrict__ t2h, float* __restrict__ t2d) {
    __shared__ float Wl[16][DD];
    __shared__ float red[64][4][16];
    int bid = blockIdx.x;
    int sel = bid >> 7;
    int r   = bid & 127;
    int b   = r >> 5;
    int lg  = (r >> 3) & 3;
    int ic  = r & 7;
    const float* src = sel ? dep : head;
    int t = threadIdx.x;

    for (int l16 = 0; l16 < 16; ++l16) {
        const float* wp = W + (size_t)(lg * 16 + l16) * (2 * DD) + sel * DD;
        Wl[l16][t]       = wp[t];
        Wl[l16][t + 256] = wp[t + 256];
        Wl[l16][t + 512] = wp[t + 512];
    }
    __syncthreads();

    int iq = t >> 2, dq = t & 3;
    int i  = ic * 64 + iq;
    const float* rowp = src + (size_t)(b * S + i) * DD;
    float acc[16];
#pragma unroll
    for (int l16 = 0; l16 < 16; ++l16) acc[l16] = 0.f;
    for (int it = 0; it < 48; ++it) {
        int d = dq * 4 + it * 16;
        float4 x = *(const float4*)(rowp + d);
#pragma unroll
        for (int l16 = 0; l16 < 16; ++l16) {
            float4 wv = *(const float4*)&Wl[l16][d];
            acc[l16] += x.x * wv.x + x.y * wv.y + x.z * wv.z + x.w * wv.w;
        }
    }
#pragma unroll
    for (int l16 = 0; l16 < 16; ++l16) red[iq][dq][l16] = acc[l16];
    __syncthreads();

    int iq2 = t >> 2, l4 = t & 3;
    float* dst = sel ? t2d : t2h;
#pragma unroll
    for (int j = 0; j < 4; ++j) {
        int l16 = l4 * 4 + j;
        float v = red[iq2][0][l16] + red[iq2][1][l16] + red[iq2][2][l16] + red[iq2][3][l16];
        if (sel) v += bias[lg * 16 + l16];
        dst[(size_t)(b * LL + lg * 16 + l16) * S + ic * 64 + iq2] = v;
    }
}

// ---------------- main: 128x128 tile, BK=32, 4 waves, TRIPLE-buffered, distance-2 ----------------
// Counted-vmcnt pipeline: step kt issues loads for kt+2 (6 VMEM ops), computes kt, writes A for
// kt+1, then waits vmcnt(6) (in-order completion => B(kt+1) drained, kt+2's loads stay in
// flight across the raw s_barrier). No full vmcnt(0) drain in the main loop.
__device__ __forceinline__ void substep(
    int k, int cOff, int nOff, int sOff,
    const float* hp0, const float* hp1, const bf16* bg0, const bf16* bg1,
    bf16* AsB, bf16* BsB, const float* Ulds,
    int boff0, int boff1, int aoff0, int aoff1, int ca,
    const int* aFo, const int* bFo,
    float4& L0, float4& L1, float4& L2, float4& L3,     // A-load target (data for k+2)
    float4& W0, float4& W1, float4& W2, float4& W3,     // A-write source (data for k+1)
    f32x4 (&acc)[4][4])
{
    const bool stg = (k + 2) < 24;
    if (stg) {   // issue kt+2 loads first: ~2 full steps of latency cover
        async_copy16(bg0 + (k + 2) * 32, BsB + sOff + boff0);
        async_copy16(bg1 + (k + 2) * 32, BsB + sOff + boff1);
        const float* h0 = hp0 + (k + 2) * 32;
        const float* h1 = hp1 + (k + 2) * 32;
        L0 = *(const float4*)(h0);
        L1 = *(const float4*)(h0 + 4);
        L2 = *(const float4*)(h1);
        L3 = *(const float4*)(h1 + 4);
    }

    bf16x8 af[4], bfr[4];
#pragma unroll
    for (int mi = 0; mi < 4; ++mi) af[mi]  = *(const bf16x8*)(AsB + cOff + aFo[mi]);
#pragma unroll
    for (int ni = 0; ni < 4; ++ni) bfr[ni] = *(const bf16x8*)(BsB + cOff + bFo[ni]);
#pragma unroll
    for (int mi = 0; mi < 4; ++mi)
#pragma unroll
        for (int ni = 0; ni < 4; ++ni)
            acc[mi][ni] = __builtin_amdgcn_mfma_f32_16x16x32_bf16(af[mi], bfr[ni], acc[mi][ni], 0, 0, 0);

    if (k + 1 < 24) {   // scale + ds_write A for step k+1 (regs loaded last step: full-step cover)
        const float* uu = &Ulds[(k + 1) * 32 + ca * 8];
        float4 ua = *(const float4*)(uu);
        float4 ub = *(const float4*)(uu + 4);
        *(bf16x8*)(AsB + nOff + aoff0) = scale_cvt(W0, W1, ua, ub);
        *(bf16x8*)(AsB + nOff + aoff1) = scale_cvt(W2, W3, ua, ub);
    }

    if (k < 23) {
        if (stg) { asm volatile("s_waitcnt vmcnt(6) lgkmcnt(0)" ::: "memory"); }
        else     { asm volatile("s_waitcnt vmcnt(0) lgkmcnt(0)" ::: "memory"); }
        __builtin_amdgcn_s_barrier();
    }
}

__global__ __launch_bounds__(256, 3) void biaffine_main(
    const float* __restrict__ head, const bf16* __restrict__ depb,
    const float* __restrict__ U, const float* __restrict__ t2h,
    const float* __restrict__ t2d, float* __restrict__ out) {
    __shared__ __align__(16) bf16 As[3][128][32];
    __shared__ __align__(16) bf16 Bs[3][128][32];
    __shared__ __align__(16) float Ulds[DD];

    const int tid  = threadIdx.x;
    const int lane = tid & 63;
    const int w    = tid >> 6;
    const int bi0  = (blockIdx.x & 3) << 7;
    const int bo0  = (blockIdx.x >> 2) << 7;
    const int l    = blockIdx.y;
    const int b    = blockIdx.z;

    bf16* AsB = &As[0][0][0];
    bf16* BsB = &Bs[0][0][0];

    {   // stage U[l] (768 f32)
        const float* up = U + (size_t)l * DD;
        Ulds[tid]       = up[tid];
        Ulds[tid + 256] = up[tid + 256];
        Ulds[tid + 512] = up[tid + 512];
    }

    // A staging: thread handles rows r1 and r1+64; phys slot cp holds data chunk ca = cp^sw
    const int r1 = tid >> 2;
    const int cp = tid & 3;
    const int sw = (r1 >> 1) & 3;          // same for r1 and r1+64
    const int ca = cp ^ sw;
    const float* hp0 = head + (size_t)(b * S + bi0 + r1) * DD + ca * 8;
    const float* hp1 = hp0 + (size_t)64 * DD;
    const int aoff0 = r1 * 32 + cp * 8;
    const int aoff1 = (r1 + 64) * 32 + cp * 8;

    // B staging via global_load_lds: 2 insts/wave, 16 rows each, swizzle in global addr
    const int rB0 = w * 32 + (lane >> 2);
    const int rB1 = rB0 + 16;
    const int cpB = lane & 3;
    const bf16* bg0 = depb + (size_t)(b * S + bo0 + rB0) * DD + (cpB ^ ((rB0 >> 1) & 3)) * 8;
    const bf16* bg1 = depb + (size_t)(b * S + bo0 + rB1) * DD + (cpB ^ ((rB1 >> 1) & 3)) * 8;
    const int boff0 = (w * 32) * 32;       // wave-uniform LDS element offsets
    const int boff1 = (w * 32 + 16) * 32;

    // fragment element offsets (constant across K loop)
    const int wr = w & 1, wc = w >> 1;
    const int mrow = lane & 15, q = lane >> 4;
    int aFo[4], bFo[4];
#pragma unroll
    for (int mi = 0; mi < 4; ++mi) {
        int rowA = wr * 64 + mi * 16 + mrow;
        aFo[mi] = rowA * 32 + ((q ^ ((rowA >> 1) & 3)) * 8);
        int rowB = wc * 64 + mi * 16 + mrow;
        bFo[mi] = rowB * 32 + ((q ^ ((rowB >> 1) & 3)) * 8);
    }

    f32x4 acc[4][4];
#pragma unroll
    for (int mi = 0; mi < 4; ++mi)
#pragma unroll
        for (int ni = 0; ni < 4; ++ni)
            acc[mi][ni] = (f32x4){0.f, 0.f, 0.f, 0.f};

    // named A-register sets (static indexing only — rule #20)
    float4 aP0, aP1, aP2, aP3;   // even steps load here; odd steps write from here
    float4 aQ0, aQ1, aQ2, aQ3;   // odd steps load here; even steps write from here

    // ---- prologue: stage steps 0 (via aP) and 1 (via aQ) ----
    aP0 = *(const float4*)(hp0);      aP1 = *(const float4*)(hp0 + 4);
    aP2 = *(const float4*)(hp1);      aP3 = *(const float4*)(hp1 + 4);
    aQ0 = *(const float4*)(hp0 + 32); aQ1 = *(const float4*)(hp0 + 36);
    aQ2 = *(const float4*)(hp1 + 32); aQ3 = *(const float4*)(hp1 + 36);
    async_copy16(bg0,      BsB + boff0);
    async_copy16(bg1,      BsB + boff1);
    async_copy16(bg0 + 32, BsB + 4096 + boff0);
    async_copy16(bg1 + 32, BsB + 4096 + boff1);
    __syncthreads();               // Ulds visible; prologue loads drained
    {
        const float* uu0 = &Ulds[ca * 8];
        float4 ua = *(const float4*)(uu0);
        float4 ub = *(const float4*)(uu0 + 4);
        *(bf16x8*)(AsB + aoff0) = scale_cvt(aP0, aP1, ua, ub);
        *(bf16x8*)(AsB + aoff1) = scale_cvt(aP2, aP3, ua, ub);
        const float* uu1 = &Ulds[32 + ca * 8];
        float4 uc = *(const float4*)(uu1);
        float4 ud = *(const float4*)(uu1 + 4);
        *(bf16x8*)(AsB + 4096 + aoff0) = scale_cvt(aQ0, aQ1, uc, ud);
        *(bf16x8*)(AsB + 4096 + aoff1) = scale_cvt(aQ2, aQ3, uc, ud);
    }
    asm volatile("s_waitcnt lgkmcnt(0)" ::: "memory");
    __builtin_amdgcn_s_barrier();   // steps 0 and 1 staged

    // ---- main loop: rotating 3-buffer offsets; aP/aQ parity via 2-step body ----
    int cOff = 0, nOff = 4096, sOff = 8192;
#pragma unroll 1
    for (int kt = 0; kt < 24; kt += 2) {
        // even sub-step: load A(kt+2) into aP, write A(kt+1) from aQ
        substep(kt, cOff, nOff, sOff, hp0, hp1, bg0, bg1, AsB, BsB, Ulds,
                boff0, boff1, aoff0, aoff1, ca, aFo, bFo,
                aP0, aP1, aP2, aP3, aQ0, aQ1, aQ2, aQ3, acc);
        { int t0 = cOff; cOff = nOff; nOff = sOff; sOff = t0; }
        // odd sub-step: load A(kt+3) into aQ, write A(kt+2) from aP
        substep(kt + 1, cOff, nOff, sOff, hp0, hp1, bg0, bg1, AsB, BsB, Ulds,
                boff0, boff1, aoff0, aoff1, ca, aFo, bFo,
                aQ0, aQ1, aQ2, aQ3, aP0, aP1, aP2, aP3, acc);
        { int t0 = cOff; cOff = nOff; nOff = sOff; sOff = t0; }
    }

    // ---- epilogue: + t2h[row] + t2d'[col] ----
    const size_t bl = (size_t)(b * LL + l);
    const float* t2hp = t2h + bl * S + bi0 + wr * 64;
    const float* t2dp = t2d + bl * S + bo0 + wc * 64;
    float* outbase = out + bl * (size_t)(S * S);
#pragma unroll
    for (int mi = 0; mi < 4; ++mi) {
        float4 th = *(const float4*)&t2hp[mi * 16 + q * 4];
        int row0 = bi0 + wr * 64 + mi * 16 + q * 4;
#pragma unroll
        for (int ni = 0; ni < 4; ++ni) {
            int col = bo0 + wc * 64 + ni * 16 + mrow;
            float td = t2dp[ni * 16 + mrow];
            float* op = outbase + (size_t)row0 * S + col;
            op[0 * S] = acc[mi][ni][0] + th.x + td;
            op[1 * S] = acc[mi][ni][1] + th.y + td;
            op[2 * S] = acc[mi][ni][2] + th.z + td;
            op[3 * S] = acc[mi][ni][3] + th.w + td;
        }
    }
}

extern "C" void kernel_launch(void* const* d_in, const int* in_sizes, int n_in,
                              void* d_out, int out_size, void* d_ws, size_t ws_size,
                              hipStream_t stream) {
    const float* head = (const float*)d_in[0];
    const float* dep  = (const float*)d_in[1];
    const float* U    = (const float*)d_in[2];
    const float* W    = (const float*)d_in[3];
    const float* bias = (const float*)d_in[4];
    float* out = (float*)d_out;

    char*  ws   = (char*)d_ws;
    bf16*  depb = (bf16*)ws;                               // B*S*D*2   = 3,145,728 B
    float* t2h  = (float*)(ws + 3145728);                  // B*L*S*4   =   524,288 B
    float* t2d  = (float*)(ws + 3145728 + 524288);         // B*L*S*4   =   524,288 B

    cvt_dep_kernel<<<768, 256, 0, stream>>>(dep, depb);
    t2_kernel<<<256, 256, 0, stream>>>(head, dep, W, bias, t2h, t2d);
    biaffine_main<<<dim3(16, LL, BB), 256, 0, stream>>>(head, depb, U, t2h, t2d, out);
}